// Round 2
// baseline (616.522 us; speedup 1.0000x reference)
//
#include <hip/hip_runtime.h>

// ============================================================================
// Qudit gate apply: state (4,)^12 complex (f32 re/im planes), gate 1024x1024
// complex on target axes (0,3,5,8,11).
// Formulated as GEMM: C[b][n] = sum_k A[b][k] * Bt[n][k]
//   A[b][k]  : k<1024 -> qs_re gathered at (b, c=k); k>=1024 -> qs_im
//   Bt[n][k] : complex-as-real blocks [[Gr, -Gi],[Gi, Gr]] (transposed layout)
//   C[b][n]  : n<1024 -> out_re at (b, r=n); else out_im
// Precision: split-bf16 (x = hi + lo), 3 MFMA terms hh+hl+lh -> ~2^-17 rel err.
// Structure: m97-class 128x128xBK64, 4 waves, global_load_lds(16B),
// XOR-swizzled LDS, + XCD-aware nt-major block swizzle (B panels L2-resident).
// ============================================================================

typedef unsigned short u16;
typedef unsigned int u32;
typedef __bf16 bf16x8 __attribute__((ext_vector_type(8)));
typedef float f32x4 __attribute__((ext_vector_type(4)));

// ---- digit scatter helpers -------------------------------------------------
// batch digits (LSB first) -> axes 10,9,7,6,4,2,1 with float strides
// 4,16,256,1024,16384,262144,1048576
__device__ __forceinline__ int scat_b(int b) {
    return ((b & 3) << 2) + (((b >> 2) & 3) << 4) + (((b >> 4) & 3) << 8) +
           (((b >> 6) & 3) << 10) + (((b >> 8) & 3) << 14) +
           (((b >> 10) & 3) << 18) + (((b >> 12) & 3) << 20);
}
// target digits: c = c0*256+c1*64+c2*16+c3*4+c4 -> axes 0,3,5,8,11
// strides 4194304,65536,4096,64,1
__device__ __forceinline__ int scat_c(int c) {
    return (c & 3) + (((c >> 2) & 3) << 6) + (((c >> 4) & 3) << 12) +
           (((c >> 6) & 3) << 16) + (((c >> 8) & 3) << 22);
}

// f32 -> bf16 hi (RNE) + bf16 lo (residual, RNE)
__device__ __forceinline__ void bsplit(float x, u16& h, u16& l) {
    u32 b  = __float_as_uint(x);
    u32 hb = (b + 0x7FFFu + ((b >> 16) & 1u)) & 0xFFFF0000u;
    h = (u16)(hb >> 16);
    float r = x - __uint_as_float(hb);
    u32 rb = __float_as_uint(r);
    l = (u16)((rb + 0x7FFFu + ((rb >> 16) & 1u)) >> 16);
}

__device__ __forceinline__ f32x4 mfma16(bf16x8 a, bf16x8 b, f32x4 c) {
    return __builtin_amdgcn_mfma_f32_16x16x32_bf16(a, b, c, 0, 0, 0);
}

__device__ __forceinline__ void gll16(const void* g, void* l) {
    __builtin_amdgcn_global_load_lds(
        (const __attribute__((address_space(1))) u32*)g,
        (__attribute__((address_space(3))) u32*)l, 16, 0, 0);
}

// ============================================================================
// pack_gate: Bt[n][k] bf16 hi/lo, n-major rows of 2048.  grid 2048 x 256
// ============================================================================
__global__ void pack_gate(const float* __restrict__ gre,
                          const float* __restrict__ gim,
                          u16* __restrict__ bh, u16* __restrict__ bl) {
    int t = blockIdx.x * 256 + threadIdx.x;  // 524288 threads
    int n = t >> 8;                          // 0..2047
    int k = (t & 255) << 3;                  // 8-elem segment
    bool nim = n >= 1024, kim = k >= 1024;
    const float* src = kim ? (nim ? gre : gim) : (nim ? gim : gre);
    float sgn = (kim && !nim) ? -1.f : 1.f;
    int r = n & 1023, c = k & 1023;
    const float* p = src + r * 1024 + c;
    float4 v0 = *(const float4*)p;
    float4 v1 = *(const float4*)(p + 4);
    u16 h[8], l[8];
    bsplit(v0.x * sgn, h[0], l[0]); bsplit(v0.y * sgn, h[1], l[1]);
    bsplit(v0.z * sgn, h[2], l[2]); bsplit(v0.w * sgn, h[3], l[3]);
    bsplit(v1.x * sgn, h[4], l[4]); bsplit(v1.y * sgn, h[5], l[5]);
    bsplit(v1.z * sgn, h[6], l[6]); bsplit(v1.w * sgn, h[7], l[7]);
    size_t o = (size_t)n * 2048 + k;
    uint4 hw, lw;
    hw.x = h[0] | ((u32)h[1] << 16); hw.y = h[2] | ((u32)h[3] << 16);
    hw.z = h[4] | ((u32)h[5] << 16); hw.w = h[6] | ((u32)h[7] << 16);
    lw.x = l[0] | ((u32)l[1] << 16); lw.y = l[2] | ((u32)l[3] << 16);
    lw.z = l[4] | ((u32)l[5] << 16); lw.w = l[6] | ((u32)l[7] << 16);
    *(uint4*)(bh + o) = hw;
    *(uint4*)(bl + o) = lw;
}

// ============================================================================
// pack_state: A[b][k] bf16 hi/lo.  Each thread: 4 consecutive b x 8 k.
// grid 4096 x 256  (1,048,576 threads x 32 elems)
// ============================================================================
__global__ void pack_state(const float* __restrict__ qre,
                           const float* __restrict__ qim,
                           u16* __restrict__ ah, u16* __restrict__ al) {
    int t = blockIdx.x * 256 + threadIdx.x;
    int seg = t & 255;       // k = seg*8
    int b0 = (t >> 8) << 2;  // 4 rows
    int k = seg << 3;
    const float* src = (k < 1024) ? qre : qim;
    int c = k & 1023;
    int cof = (((c >> 2) & 3) << 6) + (((c >> 4) & 3) << 12) +
              (((c >> 6) & 3) << 16) + (((c >> 8) & 3) << 22);
    int bb = scat_b(b0);
#pragma unroll
    for (int i = 0; i < 4; ++i) {
        const float* p = src + bb + i * 4 + cof;
        float4 v0 = *(const float4*)p;
        float4 v1 = *(const float4*)(p + 64);  // next c3 digit
        u16 h[8], l[8];
        bsplit(v0.x, h[0], l[0]); bsplit(v0.y, h[1], l[1]);
        bsplit(v0.z, h[2], l[2]); bsplit(v0.w, h[3], l[3]);
        bsplit(v1.x, h[4], l[4]); bsplit(v1.y, h[5], l[5]);
        bsplit(v1.z, h[6], l[6]); bsplit(v1.w, h[7], l[7]);
        size_t o = (size_t)(b0 + i) * 2048 + k;
        uint4 hw, lw;
        hw.x = h[0] | ((u32)h[1] << 16); hw.y = h[2] | ((u32)h[3] << 16);
        hw.z = h[4] | ((u32)h[5] << 16); hw.w = h[6] | ((u32)h[7] << 16);
        lw.x = l[0] | ((u32)l[1] << 16); lw.y = l[2] | ((u32)l[3] << 16);
        lw.z = l[4] | ((u32)l[5] << 16); lw.w = l[6] | ((u32)l[7] << 16);
        *(uint4*)(ah + o) = hw;
        *(uint4*)(al + o) = lw;
    }
}

// ============================================================================
// GEMM:  BM=BN=128, BK=64, 256 thr (4 waves 2x2, wave tile 64x64 = 4x4 frags
// of 16x16x32).  LDS tiles XOR-swizzled: byte ^= (row&7)<<4 (2-way = free).
// APACK: A staged via global_load_lds from packed ws; else gathered f32+split.
// BPACK: same for Bt; else gathered straight from gate f32 (sign folded).
// ============================================================================
__device__ __forceinline__ void stage_packed(const u16* gh, const u16* gl,
                                             int row0, int kt, u16* sh,
                                             u16* sl, int wid, int lane) {
#pragma unroll
    for (int i = 0; i < 4; ++i) {
        int chunk = (wid << 2) + i;         // 16 chunks of 8 rows
        int rl = (chunk << 3) + (lane >> 3);
        size_t off = (size_t)(row0 + rl) * 2048 + kt +
                     (((lane & 7) ^ (rl & 7)) << 3);  // pre-swizzled source
        gll16(gh + off, sh + chunk * 512);  // dest wave-uniform, linear
        gll16(gl + off, sl + chunk * 512);
    }
}

__device__ __forceinline__ void cvtwrite(const float4 v[8], int row, int half,
                                         char* sh, char* sl) {
    int swz = (row & 7) << 4;
#pragma unroll
    for (int q = 0; q < 8; ++q) {
        u16 h0, h1, h2, h3, l0, l1, l2, l3;
        bsplit(v[q].x, h0, l0); bsplit(v[q].y, h1, l1);
        bsplit(v[q].z, h2, l2); bsplit(v[q].w, h3, l3);
        int off = row * 128 + (((half << 6) + (q << 3)) ^ swz);
        uint2 hw, lw;
        hw.x = h0 | ((u32)h1 << 16); hw.y = h2 | ((u32)h3 << 16);
        lw.x = l0 | ((u32)l1 << 16); lw.y = l2 | ((u32)l3 << 16);
        *(uint2*)(sh + off) = hw;
        *(uint2*)(sl + off) = lw;
    }
}

// A gather: 8 c-quads for (row, half) of tile at kt
__device__ __forceinline__ void loadA(const float* qre, const float* qim,
                                      int bb, int half, int kt, float4 v[8]) {
    const float* src = (kt < 1024) ? qre : qim;
    int km = kt & 1023;  // only c1,c0 digits set (kt multiple of 64)
    int cof = (((km >> 6) & 3) << 16) + (((km >> 8) & 3) << 22);
    const float* p = src + bb + cof + (half << 13);  // half -> c2 bit1 (8192)
    v[0] = *(const float4*)(p);
    v[1] = *(const float4*)(p + 64);
    v[2] = *(const float4*)(p + 128);
    v[3] = *(const float4*)(p + 192);
    v[4] = *(const float4*)(p + 4096);
    v[5] = *(const float4*)(p + 4160);
    v[6] = *(const float4*)(p + 4224);
    v[7] = *(const float4*)(p + 4288);
}

// B gather from gate f32 (no-ws fallback); sign folded via sgn
__device__ __forceinline__ void loadB(const float* gre, const float* gim,
                                      int n0, int kt, int row, int half,
                                      float4 v[8], float& sgn) {
    bool nim = n0 >= 1024, kim = kt >= 1024;
    const float* src = kim ? (nim ? gre : gim) : (nim ? gim : gre);
    sgn = (kim && !nim) ? -1.f : 1.f;
    int r = (n0 + row) & 1023;
    const float* p = src + r * 1024 + (kt & 1023) + (half << 5);
#pragma unroll
    for (int q = 0; q < 8; ++q) v[q] = *(const float4*)(p + q * 4);
}

template <bool APACK, bool BPACK>
__global__ __launch_bounds__(256, 2) void gemm_k(
    const float* __restrict__ qre, const float* __restrict__ qim,
    const float* __restrict__ gre, const float* __restrict__ gim,
    const u16* __restrict__ Ah, const u16* __restrict__ Al,
    const u16* __restrict__ Bh, const u16* __restrict__ Bl,
    float* __restrict__ out) {
    __shared__ __align__(16) u16 sAh[128 * 64];
    __shared__ __align__(16) u16 sAl[128 * 64];
    __shared__ __align__(16) u16 sBh[128 * 64];
    __shared__ __align__(16) u16 sBl[128 * 64];

    int tid = threadIdx.x;
    int lane = tid & 63, wid = tid >> 6;

    // XCD-aware bijective swizzle (2048 % 8 == 0), nt-major decomposition:
    // XCD x owns orig in [x*256, (x+1)*256) = 2 nt-panels x 128 mt
    // -> 2 MB of packed B stays L2-resident per XCD; A streams via L3.
    int bid = blockIdx.x;
    int orig = ((bid & 7) << 8) + (bid >> 3);
    int nt = orig >> 7, mt = orig & 127;
    int m0 = mt << 7, n0 = nt << 7;

    // staging role
    int srow = tid >> 1, shalf = tid & 1;
    int bb = 0;
    if constexpr (!APACK) bb = scat_b(m0 + srow);

    float4 av[8], bv[8];
    float bsgn = 1.f;
    if constexpr (!APACK) loadA(qre, qim, bb, shalf, 0, av);
    if constexpr (!BPACK) loadB(gre, gim, n0, 0, srow, shalf, bv, bsgn);
    if constexpr (APACK) stage_packed(Ah, Al, m0, 0, sAh, sAl, wid, lane);
    if constexpr (BPACK) stage_packed(Bh, Bl, n0, 0, sBh, sBl, wid, lane);

    // compute role
    int wm = wid >> 1, wn = wid & 1;
    int aoffs[4], boffs[4];
#pragma unroll
    for (int f = 0; f < 4; ++f) {
        aoffs[f] = (wm * 64 + f * 16 + (lane & 15)) * 128;
        boffs[f] = (wn * 64 + f * 16 + (lane & 15)) * 128;
    }
    int swz = (lane & 7) << 4;
    int koff0 = (((lane >> 4) << 4)) ^ swz;
    int koff1 = (64 + ((lane >> 4) << 4)) ^ swz;

    f32x4 acc[4][4];
#pragma unroll
    for (int i = 0; i < 4; ++i)
#pragma unroll
        for (int j = 0; j < 4; ++j) acc[i][j] = (f32x4){0.f, 0.f, 0.f, 0.f};

    for (int it = 0; it < 32; ++it) {
        int kt = it << 6;
        if constexpr (!APACK) cvtwrite(av, srow, shalf, (char*)sAh, (char*)sAl);
        if constexpr (!BPACK) {
            // sign folded by scaling loaded values before split
            float4 bs[8];
#pragma unroll
            for (int q = 0; q < 8; ++q) {
                bs[q].x = bv[q].x * bsgn; bs[q].y = bv[q].y * bsgn;
                bs[q].z = bv[q].z * bsgn; bs[q].w = bv[q].w * bsgn;
            }
            cvtwrite(bs, srow, shalf, (char*)sBh, (char*)sBl);
        }
        __syncthreads();  // LDS writes + global_load_lds(kt) complete
        if (it < 31) {    // prefetch next gathered tiles into regs
            if constexpr (!APACK) loadA(qre, qim, bb, shalf, kt + 64, av);
            if constexpr (!BPACK)
                loadB(gre, gim, n0, kt + 64, srow, shalf, bv, bsgn);
        }
#pragma unroll
        for (int ks = 0; ks < 2; ++ks) {
            int ko = ks ? koff1 : koff0;
            bf16x8 a_h[4], a_l[4], b_h[4], b_l[4];
#pragma unroll
            for (int f = 0; f < 4; ++f) {
                a_h[f] = *(const bf16x8*)((const char*)sAh + aoffs[f] + ko);
                a_l[f] = *(const bf16x8*)((const char*)sAl + aoffs[f] + ko);
                b_h[f] = *(const bf16x8*)((const char*)sBh + boffs[f] + ko);
                b_l[f] = *(const bf16x8*)((const char*)sBl + boffs[f] + ko);
            }
#pragma unroll
            for (int i = 0; i < 4; ++i)
#pragma unroll
                for (int j = 0; j < 4; ++j) {
                    acc[i][j] = mfma16(a_h[i], b_h[j], acc[i][j]);
                    acc[i][j] = mfma16(a_l[i], b_h[j], acc[i][j]);
                    acc[i][j] = mfma16(a_h[i], b_l[j], acc[i][j]);
                }
        }
        __syncthreads();  // frag reads done before next overwrite
        if (it < 31) {
            if constexpr (APACK)
                stage_packed(Ah, Al, m0, kt + 64, sAh, sAl, wid, lane);
            if constexpr (BPACK)
                stage_packed(Bh, Bl, n0, kt + 64, sBh, sBl, wid, lane);
        }
    }

    // epilogue: scatter f32 directly into state layout
    int mbase = scat_b(m0 + wm * 64);
    int nw = n0 + wn * 64;
    float* op = out + ((nw >> 10) << 24);  // re plane or im plane (+16M)
    int rb = nw & 1023;
    int rbase = (((rb >> 2) & 3) << 6) + (((rb >> 4) & 3) << 12) +
                (((rb >> 6) & 3) << 16) + (((rb >> 8) & 3) << 22);
    int loff = ((lane >> 4) << 4) + (((lane >> 2) & 3) << 6) + (lane & 3);
#pragma unroll
    for (int i = 0; i < 4; ++i)
#pragma unroll
        for (int j = 0; j < 4; ++j) {
            int base = mbase + rbase + loff + i * 256 + j * 4096;
            op[base]      = acc[i][j][0];
            op[base + 4]  = acc[i][j][1];   // D row digit -> axis10 (stride 4)
            op[base + 8]  = acc[i][j][2];
            op[base + 12] = acc[i][j][3];
        }
}

// ============================================================================
extern "C" void kernel_launch(void* const* d_in, const int* in_sizes, int n_in,
                              void* d_out, int out_size, void* d_ws,
                              size_t ws_size, hipStream_t stream) {
    const float* qre = (const float*)d_in[0];
    const float* qim = (const float*)d_in[1];
    const float* gre = (const float*)d_in[2];
    const float* gim = (const float*)d_in[3];
    float* out = (float*)d_out;

    const size_t BT_BYTES = 2048ull * 2048 * 2 * 2;   // 16 MB
    const size_t A_BYTES = 16384ull * 2048 * 2 * 2;   // 128 MB
    u16* Bh = (u16*)d_ws;
    u16* Bl = Bh + 2048ull * 2048;
    u16* Ah = (u16*)((char*)d_ws + BT_BYTES);
    u16* Al = Ah + 16384ull * 2048;

    bool haveB = ws_size >= BT_BYTES;
    bool haveA = ws_size >= BT_BYTES + A_BYTES;

    if (haveB) pack_gate<<<2048, 256, 0, stream>>>(gre, gim, Bh, Bl);
    if (haveA) pack_state<<<4096, 256, 0, stream>>>(qre, qim, Ah, Al);

    if (haveA)
        gemm_k<true, true><<<2048, 256, 0, stream>>>(qre, qim, gre, gim, Ah,
                                                     Al, Bh, Bl, out);
    else if (haveB)
        gemm_k<false, true><<<2048, 256, 0, stream>>>(qre, qim, gre, gim, Ah,
                                                      Al, Bh, Bl, out);
    else
        gemm_k<false, false><<<2048, 256, 0, stream>>>(qre, qim, gre, gim, Ah,
                                                       Al, Bh, Bl, out);
}